// Round 6
// baseline (79.589 us; speedup 1.0000x reference)
//
#include <hip/hip_runtime.h>
#include <hip/hip_bf16.h>

#define NN   2048
#define DDIM 128
#define HH   8
#define DHH  16
#define NEDGE 65536
#define FFN  512
#define EPSV 1e-5f
#define CAP  256
#define HSLOT 128

typedef const float* fp_c;

// int64 vs int32 index layout: int64 values < 2048 have all-zero odd words.
__device__ __forceinline__ bool idx64(const int* src) {
    return (src[1] | src[3] | src[5] | src[7] | src[9] | src[11]) == 0;
}

// ================= fused prep + QKV =================
// blocks 0..511: QKV GEMM rows 4b..4b+3.
// blocks 512..639: clear bitmap(512KB)+ehash(1MB), edge-bias mini-GEMM.
__global__ __launch_bounds__(512) void k_pq(float* Qf, float* Kf, float* Vf, fp_c x,
                                            fp_c Wq, fp_c bq, fp_c Wk, fp_c bk, fp_c Wv, fp_c bv,
                                            int* ehash, unsigned* bm, float* eb,
                                            const int* src, const int* dst,
                                            fp_c edge_feat, fp_c We, fp_c be) {
    int b = blockIdx.x;
    int t = threadIdx.x;
    if (b < 512) {
        __shared__ float sx[4][DDIM];
        __shared__ float red[3][4][4][DDIM];
        int r0 = b * 4;
        int c = t & 127;
        int ks = t >> 7;
        sx[t >> 7][t & 127] = x[r0 * DDIM + t];
        __syncthreads();
        float aq[4] = {0, 0, 0, 0}, ak[4] = {0, 0, 0, 0}, av[4] = {0, 0, 0, 0};
        int kbeg = ks * 32;
#pragma unroll 8
        for (int k = kbeg; k < kbeg + 32; k++) {
            float wq = Wq[k * DDIM + c];
            float wk = Wk[k * DDIM + c];
            float wv = Wv[k * DDIM + c];
#pragma unroll
            for (int r = 0; r < 4; r++) {
                float xv = sx[r][k];
                aq[r] += xv * wq; ak[r] += xv * wk; av[r] += xv * wv;
            }
        }
#pragma unroll
        for (int r = 0; r < 4; r++) {
            red[0][ks][r][c] = aq[r];
            red[1][ks][r][c] = ak[r];
            red[2][ks][r][c] = av[r];
        }
        __syncthreads();
        int rr = t >> 7, cc = t & 127;
        float vq = 0, vk = 0, vv = 0;
#pragma unroll
        for (int s = 0; s < 4; s++) {
            vq += red[0][s][rr][cc];
            vk += red[1][s][rr][cc];
            vv += red[2][s][rr][cc];
        }
        Qf[(r0 + rr) * DDIM + cc] = (vq + bq[cc]) * 0.25f;
        Kf[(r0 + rr) * DDIM + cc] = vk + bk[cc];
        Vf[(r0 + rr) * DDIM + cc] = vv + bv[cc];
    } else {
        __shared__ float sWe[80];
        __shared__ float sbe[8];
        if (t < 80) sWe[t] = We[t];
        if (t < 8)  sbe[t] = be[t];
        __syncthreads();
        int u = (b - 512) * 512 + t;
        if (u < NN * 64 / 4) ((int4*)bm)[u] = make_int4(0, 0, 0, 0);
        if (u < NN * HSLOT / 4) ((int4*)ehash)[u] = make_int4(0, 0, 0, 0);
        if (u < NEDGE) {
            float ef[10];
#pragma unroll
            for (int k = 0; k < 10; k++) ef[k] = edge_feat[u * 10 + k];
#pragma unroll
            for (int h = 0; h < 8; h++) {
                float a = sbe[h];
#pragma unroll
                for (int k = 0; k < 10; k++) a += ef[k] * sWe[k * 8 + h];
                eb[u * 8 + h] = a;
            }
        }
    }
}

// ---------------- scatter: hash insert (max-e on dup key) + adjacency bitmap ----------------
__global__ __launch_bounds__(512) void k_scatter(int* ehash, unsigned* bm, const int* src, const int* dst) {
    int t = blockIdx.x * blockDim.x + threadIdx.x;
    bool is64 = idx64(src);
    if (t < NEDGE) {
        int s = is64 ? src[2 * t] : src[t];
        int d = is64 ? dst[2 * t] : dst[t];
        atomicOr(&bm[s * 64 + (d >> 5)], 1u << (d & 31));
        atomicOr(&bm[d * 64 + (s >> 5)], 1u << (s & 31));
        // open-addressing insert of (key=d, val=max e) into row s
        int packed = (d << 17) | (t + 1);
        int slot = d & (HSLOT - 1);
        int* row = ehash + s * HSLOT;
#pragma unroll 1
        for (int it = 0; it < HSLOT; it++) {
            int cur = row[slot];
            if (cur == 0) {
                int old = atomicCAS(&row[slot], 0, packed);
                if (old == 0) break;
                cur = old;
            }
            if ((cur >> 17) == d) { atomicMax(&row[slot], packed); break; }
            slot = (slot + 1) & (HSLOT - 1);
        }
    } else if (t < NEDGE + NN) {
        int i = t - NEDGE;
        atomicOr(&bm[i * 64 + (i >> 5)], 1u << (i & 31));
    }
}

// ---------------- sparse masked attention: 256 threads (4 waves) per row ----------------
__global__ __launch_bounds__(256) void k_attn(float* attn_out, const float* Qf, const float* Kf,
                                              const float* Vf, const int* ehash, const float* eb,
                                              const unsigned* bm) {
    __shared__ float qrow[DDIM];
    __shared__ int   lj[CAP + 8];
    __shared__ int   lev[CAP + 8];
    __shared__ float sc[CAP + 8][HH];
    __shared__ float hinv[HH];
    __shared__ float redpv[2][DDIM];
    __shared__ int   scnt;
    int i = blockIdx.x;
    int t = threadIdx.x;
    if (t < 128) qrow[t] = Qf[i * DDIM + t];

    // phase 1 (wave 0): bitmap -> compacted neighbor list (ascending j)
    if (t < 64) {
        unsigned word = bm[i * 64 + t];
        int pc = __popc(word);
        int x = pc;
#pragma unroll
        for (int off = 1; off < 64; off <<= 1) {
            int y = __shfl_up(x, off);
            if (t >= off) x += y;
        }
        int cnt = __shfl(x, 63);
        if (cnt > CAP - 8) cnt = CAP - 8;
        int idx = x - pc;
        unsigned w = word;
        while (w && idx < CAP) {
            int bpos = __ffs(w) - 1;
            lj[idx++] = (t << 5) + bpos;
            w &= w - 1;
        }
        if (t < 8) lj[cnt + t] = 0;  // pad slots
        if (t == 0) scnt = cnt;
    }
    __syncthreads();
    int cnt = scnt;
    int cnt8 = (cnt + 7) & ~7;
    // hash lookup: edge id for forward edge (i->j), else -1 (no bias)
    if (t < cnt8) {
        int e = -1;
        if (t < cnt) {
            int j = lj[t];
            const int* row = ehash + i * HSLOT;
            int slot = j & (HSLOT - 1);
#pragma unroll 1
            for (int it = 0; it < HSLOT; it++) {
                int v = row[slot];
                if (v == 0) break;
                if ((v >> 17) == j) { e = (v & 0x1FFFF) - 1; break; }
                slot = (slot + 1) & (HSLOT - 1);
            }
        }
        lev[t] = e;
    }
    __syncthreads();

    // phase 2: scores — 32 neighbor slots x 8 heads in parallel
    int h = t & 7;
    int nsl = t >> 3;
    const float4* q4 = (const float4*)(qrow + h * DHH);
    float4 q0 = q4[0], q1 = q4[1], q2 = q4[2], q3 = q4[3];
    for (int n = nsl; n < cnt8; n += 32) {
        int j = lj[n];
        const float4* k4 = (const float4*)(Kf + j * DDIM + h * DHH);
        float4 k0 = k4[0], k1 = k4[1], k2 = k4[2], k3 = k4[3];
        float s = q0.x * k0.x + q0.y * k0.y + q0.z * k0.z + q0.w * k0.w
                + q1.x * k1.x + q1.y * k1.y + q1.z * k1.z + q1.w * k1.w
                + q2.x * k2.x + q2.y * k2.y + q2.z * k2.z + q2.w * k2.w
                + q3.x * k3.x + q3.y * k3.y + q3.z * k3.z + q3.w * k3.w;
        int ev = lev[n];
        if (ev >= 0) s += eb[ev * 8 + h];
        sc[n][h] = s;
    }
    __syncthreads();

    // phase 3: per-head softmax — 32 threads per head
    {
        int hh = t >> 5;
        int sub = t & 31;
        float m = -1e30f;
        for (int n = sub; n < cnt; n += 32) m = fmaxf(m, sc[n][hh]);
#pragma unroll
        for (int off = 1; off < 32; off <<= 1) m = fmaxf(m, __shfl_xor(m, off));
        float ssum = 0.f;
        for (int n = sub; n < cnt; n += 32) {
            float e = __expf(sc[n][hh] - m);
            sc[n][hh] = e;
            ssum += e;
        }
#pragma unroll
        for (int off = 1; off < 32; off <<= 1) ssum += __shfl_xor(ssum, off);
        if (sub == 0) hinv[hh] = 1.0f / ssum;
    }
    // zero pad rows (<=7 rows x 8 heads, threads 0..63)
    if (t < 64) {
        int p = cnt + (t >> 3);
        if (p < cnt8) sc[p][t & 7] = 0.f;
    }
    __syncthreads();

    // phase 4: PV — neighbors split across 2 groups of 128 threads
    {
        int g = t >> 7, c = t & 127, h2 = c >> 4;
        float a = 0.f;
#pragma unroll 4
        for (int n = g; n < cnt8; n += 2)
            a += sc[n][h2] * Vf[lj[n] * DDIM + c];
        redpv[g][c] = a;
    }
    __syncthreads();
    if (t < 128)
        attn_out[i * DDIM + t] = (redpv[0][t] + redpv[1][t]) * hinv[t >> 4];
}

// ================= fused tail: Wo+LN1 -> FFN1 -> FFN2+LN2 =================
__global__ __launch_bounds__(512) void k_tail(float* out, const float* ain,
                                              fp_c Wo, fp_c bo, fp_c node, fp_c g1, fp_c b1,
                                              fp_c W1, fp_c bf1, fp_c W2, fp_c bf2,
                                              fp_c g2, fp_c b2) {
    __shared__ float sa[4][DDIM];
    __shared__ float red[4][4][DDIM];
    __shared__ float x1ld[4][DDIM];
    __shared__ float sh[4][FFN];
    __shared__ float2 sc2[8];
    int t = threadIdx.x;
    int r0 = blockIdx.x * 4;
    int c = t & 127;
    int ks = t >> 7;
    int rr = t >> 7, cc = t & 127;
    sa[t >> 7][t & 127] = ain[r0 * DDIM + t];
    __syncthreads();

    // phase A: Wo proj (K-split 4) + bias + residual + LN1 -> x1ld
    {
        float acc[4] = {0, 0, 0, 0};
        int kbeg = ks * 32;
#pragma unroll 8
        for (int k = kbeg; k < kbeg + 32; k++) {
            float w = Wo[k * DDIM + c];
#pragma unroll
            for (int r = 0; r < 4; r++) acc[r] += sa[r][k] * w;
        }
#pragma unroll
        for (int r = 0; r < 4; r++) red[ks][r][c] = acc[r];
        __syncthreads();
        float val = red[0][rr][cc] + red[1][rr][cc] + red[2][rr][cc] + red[3][rr][cc];
        val += bo[cc] + node[(r0 + rr) * DDIM + cc];
        float vs = val, vq = val * val;
#pragma unroll
        for (int off = 32; off >= 1; off >>= 1) {
            vs += __shfl_down(vs, off);
            vq += __shfl_down(vq, off);
        }
        if ((t & 63) == 0) sc2[t >> 6] = make_float2(vs, vq);
        __syncthreads();
        float sum = sc2[2 * rr].x + sc2[2 * rr + 1].x;
        float sq  = sc2[2 * rr].y + sc2[2 * rr + 1].y;
        float mu = sum * (1.0f / DDIM);
        float var = sq * (1.0f / DDIM) - mu * mu;
        x1ld[rr][cc] = (val - mu) * rsqrtf(var + EPSV) * g1[cc] + b1[cc];
    }
    __syncthreads();

    // phase B: hidden = relu(x1 @ W1 + bf1), column t of 512
    {
        float acc[4] = {0, 0, 0, 0};
#pragma unroll 8
        for (int k = 0; k < DDIM; k++) {
            float w = W1[k * FFN + t];
#pragma unroll
            for (int r = 0; r < 4; r++) acc[r] += x1ld[r][k] * w;
        }
        float bb = bf1[t];
#pragma unroll
        for (int r = 0; r < 4; r++) sh[r][t] = fmaxf(acc[r] + bb, 0.f);
    }
    __syncthreads();

    // phase C: ffn2 (K-split 4 over 512) + bias + residual + LN2 -> out
    {
        float acc[4] = {0, 0, 0, 0};
        int kbeg = ks * 128;
#pragma unroll 8
        for (int k = kbeg; k < kbeg + 128; k++) {
            float w = W2[k * DDIM + c];
#pragma unroll
            for (int r = 0; r < 4; r++) acc[r] += sh[r][k] * w;
        }
#pragma unroll
        for (int r = 0; r < 4; r++) red[ks][r][c] = acc[r];
        __syncthreads();
        float val = red[0][rr][cc] + red[1][rr][cc] + red[2][rr][cc] + red[3][rr][cc];
        val += bf2[cc] + x1ld[rr][cc];
        float vs = val, vq = val * val;
#pragma unroll
        for (int off = 32; off >= 1; off >>= 1) {
            vs += __shfl_down(vs, off);
            vq += __shfl_down(vq, off);
        }
        if ((t & 63) == 0) sc2[t >> 6] = make_float2(vs, vq);
        __syncthreads();
        float sum = sc2[2 * rr].x + sc2[2 * rr + 1].x;
        float sq  = sc2[2 * rr].y + sc2[2 * rr + 1].y;
        float mu = sum * (1.0f / DDIM);
        float var = sq * (1.0f / DDIM) - mu * mu;
        out[(r0 + rr) * DDIM + cc] = (val - mu) * rsqrtf(var + EPSV) * g2[cc] + b2[cc];
    }
}

extern "C" void kernel_launch(void* const* d_in, const int* in_sizes, int n_in,
                              void* d_out, int out_size, void* d_ws, size_t ws_size,
                              hipStream_t stream) {
    fp_c node = (fp_c)d_in[0];
    fp_c edge_feat = (fp_c)d_in[1];
    const int* src = (const int*)d_in[2];
    const int* dst = (const int*)d_in[3];
    fp_c Wq = (fp_c)d_in[4];  fp_c bq = (fp_c)d_in[5];
    fp_c Wk = (fp_c)d_in[6];  fp_c bk = (fp_c)d_in[7];
    fp_c Wv = (fp_c)d_in[8];  fp_c bv = (fp_c)d_in[9];
    fp_c Wo = (fp_c)d_in[10]; fp_c bo = (fp_c)d_in[11];
    fp_c We = (fp_c)d_in[12]; fp_c be = (fp_c)d_in[13];
    fp_c g1 = (fp_c)d_in[14]; fp_c b1n = (fp_c)d_in[15];
    fp_c g2 = (fp_c)d_in[16]; fp_c b2n = (fp_c)d_in[17];
    fp_c W1 = (fp_c)d_in[18]; fp_c bf1 = (fp_c)d_in[19];
    fp_c W2 = (fp_c)d_in[20]; fp_c bf2 = (fp_c)d_in[21];

    char* ws = (char*)d_ws;
    int* ehash    = (int*)ws;      ws += (size_t)NN * HSLOT * 4;
    unsigned* bm  = (unsigned*)ws; ws += (size_t)NN * 64 * 4;
    float* eb     = (float*)ws;    ws += (size_t)NEDGE * 8 * 4;
    float* Qf     = (float*)ws;    ws += (size_t)NN * DDIM * 4;
    float* Kf     = (float*)ws;    ws += (size_t)NN * DDIM * 4;
    float* Vf     = (float*)ws;    ws += (size_t)NN * DDIM * 4;
    float* attn_o = (float*)ws;    ws += (size_t)NN * DDIM * 4;

    k_pq<<<640, 512, 0, stream>>>(Qf, Kf, Vf, node, Wq, bq, Wk, bk, Wv, bv,
                                  ehash, bm, eb, src, dst, edge_feat, We, be);
    k_scatter<<<(NEDGE + NN + 511) / 512, 512, 0, stream>>>(ehash, bm, src, dst);
    k_attn<<<NN, 256, 0, stream>>>(attn_o, Qf, Kf, Vf, ehash, eb, bm);
    k_tail<<<NN / 4, 512, 0, stream>>>((float*)d_out, attn_o, Wo, bo, node, g1, b1n,
                                       W1, bf1, W2, bf2, g2, b2n);
}